// Round 9
// baseline (5829.930 us; speedup 1.0000x reference)
//
#include <hip/hip_runtime.h>

#define TSTEPS 8192
#define H 51

typedef float f4 __attribute__((ext_vector_type(4)));

__device__ __forceinline__ float rlane(float v, int k) {
    return __int_as_float(__builtin_amdgcn_readlane(__float_as_int(v), k));
}
__device__ __forceinline__ float sigmoidf_fast(float x) {
    return __builtin_amdgcn_rcpf(1.0f + __expf(-x));
}
__device__ __forceinline__ float tanhf_fast(float x) {
    x = fminf(fmaxf(x, -15.0f), 15.0f);
    float t = __expf(-2.0f * x);
    return (1.0f - t) * __builtin_amdgcn_rcpf(1.0f + t);
}
__device__ __forceinline__ f4 fma4(f4 a, float b, f4 c) {
    f4 bv = {b, b, b, b};
    return __builtin_elementwise_fma(a, bv, c);
}
// Pin a value into VGPRs: "+v" tied operand cannot be remat'd from memory.
// Proven at 52 floats in R8 (VGPR=56, weights resident). Here: 204 floats.
#define PIN(v) asm volatile("" : "+v"(v))

#define REP51(X) X(0) X(1) X(2) X(3) X(4) X(5) X(6) X(7) X(8) X(9) \
 X(10) X(11) X(12) X(13) X(14) X(15) X(16) X(17) X(18) X(19) \
 X(20) X(21) X(22) X(23) X(24) X(25) X(26) X(27) X(28) X(29) \
 X(30) X(31) X(32) X(33) X(34) X(35) X(36) X(37) X(38) X(39) \
 X(40) X(41) X(42) X(43) X(44) X(45) X(46) X(47) X(48) X(49) X(50)

#define DECLW(i) f4 wk##i;
#define LOADW(i) { wk##i[0] = Mp[(0*H+row)*H + i]; wk##i[1] = Mp[(1*H+row)*H + i]; \
                   wk##i[2] = Mp[(2*H+row)*H + i]; wk##i[3] = Mp[(3*H+row)*H + i]; }
#define PINW(i)  PIN(wk##i);
#define DOTSTEP(i) { const float hk = rlane(_hsrc, i); _acc = fma4(wk##i, hk, _acc); }

// R9 = R6's wave-specialized pipeline (in-wave readlane broadcasts, ~14 DS
// ops/epoch — R8 showed ~200 DS ops/epoch saturate the shared LDS pipe) +
// R8's asm-pin residency (R6 spilled its 208 floats/wave: VGPR=132, ~850
// cyc/epoch of scratch reloads). 4 waves, 1/SIMD, 1 barrier/epoch:
//   wave0 @e: h1(e)   = cell1(Whh1.h1(e-1) + x[e])   [in-wave self-loop]
//   wave2 @e: z2a(e-1)= Wih2.h1(e-1)                  [1 LDS b32 read]
//   wave1 @e: h2(e-2) = cell2(u2(e-2)+z2a(e-2)); u2(e-1)=b2+Whh2.h2(e-2)
//   wave3 @e: out(e-3)= Wlin.h2(e-3)+blin             [off critical path]
// Weight layout per wave: 51 pinned f4 columns wk[k] = {W[g*H+row][k]}_g,
// so the dot is 51 x (readlane + f4-fma).
__global__ __launch_bounds__(256) __attribute__((amdgpu_waves_per_eu(1, 1)))
void lstm2_pin4_kernel(const float* __restrict__ x,
                       const float* __restrict__ Wih1,
                       const float* __restrict__ Whh1,
                       const float* __restrict__ bih1,
                       const float* __restrict__ bhh1,
                       const float* __restrict__ Wih2,
                       const float* __restrict__ Whh2,
                       const float* __restrict__ bih2,
                       const float* __restrict__ bhh2,
                       const float* __restrict__ Wlin,
                       const float* __restrict__ blin,
                       float* __restrict__ out)
{
    __shared__ __align__(16) float sh_x[TSTEPS];
    __shared__ __align__(16) float sh_out[TSTEPS];
    __shared__ __align__(16) float sh_h1[2][64];
    __shared__ __align__(16) float sh_h2[2][64];
    __shared__ __align__(16) f4    sh_z2a[2][64];

    const int tid  = threadIdx.x;
    const int wave = tid >> 6;
    const int lane = tid & 63;
    const int row  = (lane < H) ? lane : (H - 1);

    // ---- stage x (coalesced f4) ----
    for (int i = tid; i < TSTEPS / 4; i += 256)
        ((f4*)sh_x)[i] = ((const f4*)x)[i];

    // ---- per-wave matrix, 51 pinned f4 columns (wave3 loads unused Whh1) ----
    const float* Mp = (wave == 0) ? Whh1 : (wave == 1) ? Whh2 : Wih2;
    REP51(DECLW)
    REP51(LOADW)

    f4 bias1, wx4, bias2;
#pragma unroll
    for (int g = 0; g < 4; ++g) {
        bias1[g] = bih1[g * H + row] + bhh1[g * H + row];
        wx4[g]   = Wih1[g * H + row];
        bias2[g] = bih2[g * H + row] + bhh2[g * H + row];
    }
    const float wlin = (lane < H) ? Wlin[lane] : 0.0f;
    const float bl   = blin[0];

    // ---- init LDS state ----
    if (tid < 64) {
        sh_h1[0][tid] = 0.0f; sh_h1[1][tid] = 0.0f;
        sh_h2[0][tid] = 0.0f; sh_h2[1][tid] = 0.0f;
        sh_z2a[0][tid] = (f4)0.0f; sh_z2a[1][tid] = (f4)0.0f;
    }

    float h1reg = 0.0f, h2reg = 0.0f, c1 = 0.0f, c2 = 0.0f;
    f4 u2stash = bias2;   // wave1: u2(-1) = b2 (h2 init 0)

    __syncthreads();

#pragma unroll 1
    for (int e = 0; e < TSTEPS + 3; ++e) {
        REP51(PINW)

        if (wave == 0) {
            // ---- h1(e) = cell1(b1 + wx*x[e] + Whh1.h1(e-1)) — fully in-wave
            if (e < TSTEPS) {
                const float xv = sh_x[e];
                f4 _acc = fma4(wx4, xv, bias1);
                float _hsrc = h1reg;
                REP51(DOTSTEP)
                const float ig = sigmoidf_fast(_acc[0]);
                const float fg = sigmoidf_fast(_acc[1]);
                const float gg = tanhf_fast(_acc[2]);
                const float og = sigmoidf_fast(_acc[3]);
                c1 = fmaf(fg, c1, ig * gg);
                h1reg = (lane < H) ? og * tanhf_fast(c1) : 0.0f;
                sh_h1[e & 1][lane] = h1reg;
            }
        } else if (wave == 2) {
            // ---- z2a(e-1) = Wih2 . h1(e-1) ----
            if (e >= 1 && e <= TSTEPS) {
                const int s = e - 1;
                float _hsrc = sh_h1[s & 1][lane];   // written epoch e-1
                f4 _acc = (f4)0.0f;
                REP51(DOTSTEP)
                sh_z2a[s & 1][lane] = _acc;
            }
        } else if (wave == 1) {
            // ---- h2(e-2) = cell2(u2(e-2) + z2a(e-2)) ----
            if (e >= 2 && e <= TSTEPS + 1) {
                const int s = e - 2;
                const f4 za = sh_z2a[s & 1][lane];  // written epoch e-1
                const float ig = sigmoidf_fast(u2stash[0] + za[0]);
                const float fg = sigmoidf_fast(u2stash[1] + za[1]);
                const float gg = tanhf_fast   (u2stash[2] + za[2]);
                const float og = sigmoidf_fast(u2stash[3] + za[3]);
                c2 = fmaf(fg, c2, ig * gg);
                h2reg = (lane < H) ? og * tanhf_fast(c2) : 0.0f;
                sh_h2[s & 1][lane] = h2reg;
            }
            // ---- u2(e-1) = b2 + Whh2 . h2(e-2) — in-wave ----
            if (e >= 1 && e <= TSTEPS) {
                f4 _acc = bias2;
                float _hsrc = h2reg;
                REP51(DOTSTEP)
                u2stash = _acc;
            }
        } else {
            // ---- wave3: out(e-3) = Wlin.h2(e-3) + blin (off critical path)
            if (e >= 3) {
                const int s = e - 3;
                const float hv = sh_h2[s & 1][lane];   // written epoch e-1
                float p = hv * wlin;
                p += __shfl_down(p, 32);
                p += __shfl_down(p, 16);
                p += __shfl_down(p, 8);
                p += __shfl_down(p, 4);
                p += __shfl_down(p, 2);
                p += __shfl_down(p, 1);
                if (lane == 0) sh_out[s] = p + bl;
            }
        }
        __syncthreads();
    }

    // ---- bulk coalesced output store ----
    for (int i = tid; i < TSTEPS / 4; i += 256)
        ((f4*)out)[i] = ((const f4*)sh_out)[i];
}

extern "C" void kernel_launch(void* const* d_in, const int* in_sizes, int n_in,
                              void* d_out, int out_size, void* d_ws, size_t ws_size,
                              hipStream_t stream) {
    const float* x    = (const float*)d_in[0];
    const float* Wih1 = (const float*)d_in[1];
    const float* Whh1 = (const float*)d_in[2];
    const float* bih1 = (const float*)d_in[3];
    const float* bhh1 = (const float*)d_in[4];
    const float* Wih2 = (const float*)d_in[5];
    const float* Whh2 = (const float*)d_in[6];
    const float* bih2 = (const float*)d_in[7];
    const float* bhh2 = (const float*)d_in[8];
    const float* Wlin = (const float*)d_in[9];
    const float* blin = (const float*)d_in[10];
    float* out = (float*)d_out;

    lstm2_pin4_kernel<<<1, 256, 0, stream>>>(
        x, Wih1, Whh1, bih1, bhh1, Wih2, Whh2, bih2, bhh2, Wlin, blin, out);
}

// Round 10
// 4132.223 us; speedup vs baseline: 1.4108x; 1.4108x over previous
//
#include <hip/hip_runtime.h>

#define TSTEPS 8192
#define H 51

typedef float  f2 __attribute__((ext_vector_type(2)));
typedef float  f4 __attribute__((ext_vector_type(4)));
typedef int    i4 __attribute__((ext_vector_type(4)));
typedef int    i2 __attribute__((ext_vector_type(2)));
typedef _Float16 h2 __attribute__((ext_vector_type(2)));

__device__ __forceinline__ int rl_i(int v, int k) { return __builtin_amdgcn_readlane(v, k); }
__device__ __forceinline__ h2 asp(int v) { union { int i; h2 h; } u; u.i = v; return u.h; }
__device__ __forceinline__ int ash(h2 v) { union { int i; h2 h; } u; u.h = v; return u.i; }

__device__ __forceinline__ float fdot2(h2 a, h2 b, float c) {
#if __has_builtin(__builtin_amdgcn_fdot2)
    return __builtin_amdgcn_fdot2(a, b, c, false);
#else
    return fmaf((float)a[0], (float)b[0], fmaf((float)a[1], (float)b[1], c));
#endif
}
__device__ __forceinline__ float sigmoidf_fast(float x) {
    return __builtin_amdgcn_rcpf(1.0f + __expf(-x));
}
__device__ __forceinline__ float tanhf_fast(float x) {
    x = fminf(fmaxf(x, -15.0f), 15.0f);
    float t = __expf(-2.0f * x);
    return (1.0f - t) * __builtin_amdgcn_rcpf(1.0f + t);
}
// f16-RNE pack of one k-pair of a weight row
__device__ __forceinline__ int packpair(const float* Wrow, int j) {
    const float w0 = (2 * j < H) ? Wrow[2 * j] : 0.0f;
    const float w1 = (2 * j + 1 < H) ? Wrow[2 * j + 1] : 0.0f;
    h2 p; p[0] = (_Float16)w0; p[1] = (_Float16)w1; return ash(p);
}

// R10: R9's 4-wave pipeline, but the matrix HALVED in register footprint:
// f16-pair weights (104 VGPRs/wave, under the empirical 132-VGPR wall that
// made R2/R6/R9 spill) + v_dot2_f32_f16 (2 MACs/instr, fp32 accumulate).
//   wave0 @e: h1(e)   = cell1(Whh1.h1(e-1) + x[e])    [in-wave, dot2]
//   wave2 @e: z2a(e-1)= Wih2.h1(e-1)                   [dot2, 1 LDS read]
//   wave1 @e: u2(e-2) = b2+Whh2.h2(e-3) [dot2, FIRST — hides z2a latency];
//             h2(e-2) = cell2(u2 + z2a(e-2))
//   wave3 @e: out(e-3)= Wlin.h2(e-3)+blin              [off critical path]
// h packed to f16-pairs once per producer epoch via a 1-write/1-read LDS hop.
#define DECLG(g) i4 wq##g##_0, wq##g##_1, wq##g##_2, wq##g##_3, wq##g##_4, wq##g##_5; i2 wq##g##_6;
#define LOADG(g, RP) { const float* _r = (RP); \
    i4 t0 = {packpair(_r,0),  packpair(_r,1),  packpair(_r,2),  packpair(_r,3)};  wq##g##_0 = t0; \
    i4 t1 = {packpair(_r,4),  packpair(_r,5),  packpair(_r,6),  packpair(_r,7)};  wq##g##_1 = t1; \
    i4 t2 = {packpair(_r,8),  packpair(_r,9),  packpair(_r,10), packpair(_r,11)}; wq##g##_2 = t2; \
    i4 t3 = {packpair(_r,12), packpair(_r,13), packpair(_r,14), packpair(_r,15)}; wq##g##_3 = t3; \
    i4 t4 = {packpair(_r,16), packpair(_r,17), packpair(_r,18), packpair(_r,19)}; wq##g##_4 = t4; \
    i4 t5 = {packpair(_r,20), packpair(_r,21), packpair(_r,22), packpair(_r,23)}; wq##g##_5 = t5; \
    i2 t6 = {packpair(_r,24), packpair(_r,25)};                                   wq##g##_6 = t6; }
#define PING(g) asm("" : "+v"(wq##g##_0), "+v"(wq##g##_1), "+v"(wq##g##_2), \
                        "+v"(wq##g##_3), "+v"(wq##g##_4), "+v"(wq##g##_5), "+v"(wq##g##_6));
#define DJ(j,q,e) { const h2 _hb = asp(rl_i(_hs, j)); \
    a0 = fdot2(asp(wq0_##q[e]), _hb, a0); \
    a1 = fdot2(asp(wq1_##q[e]), _hb, a1); \
    a2 = fdot2(asp(wq2_##q[e]), _hb, a2); \
    a3 = fdot2(asp(wq3_##q[e]), _hb, a3); }
#define DOT26 \
    DJ(0,0,0) DJ(1,0,1) DJ(2,0,2) DJ(3,0,3) DJ(4,1,0) DJ(5,1,1) DJ(6,1,2) DJ(7,1,3) \
    DJ(8,2,0) DJ(9,2,1) DJ(10,2,2) DJ(11,2,3) DJ(12,3,0) DJ(13,3,1) DJ(14,3,2) DJ(15,3,3) \
    DJ(16,4,0) DJ(17,4,1) DJ(18,4,2) DJ(19,4,3) DJ(20,5,0) DJ(21,5,1) DJ(22,5,2) DJ(23,5,3) \
    DJ(24,6,0) DJ(25,6,1)

__global__ __launch_bounds__(256) __attribute__((amdgpu_waves_per_eu(1, 1)))
void lstm2_dot2_kernel(const float* __restrict__ x,
                       const float* __restrict__ Wih1,
                       const float* __restrict__ Whh1,
                       const float* __restrict__ bih1,
                       const float* __restrict__ bhh1,
                       const float* __restrict__ Wih2,
                       const float* __restrict__ Whh2,
                       const float* __restrict__ bih2,
                       const float* __restrict__ bhh2,
                       const float* __restrict__ Wlin,
                       const float* __restrict__ blin,
                       float* __restrict__ out)
{
    __shared__ __align__(16) float sh_x[TSTEPS];
    __shared__ __align__(16) float sh_out[TSTEPS];
    __shared__ __align__(16) float sh_h1f[64];       // wave0-private f32 h1 (pack hop)
    __shared__ __align__(16) float sh_h2f[2][64];    // f32 h2 (pack hop + wave3 input)
    __shared__ __align__(16) int   sh_hpk1[2][64];   // packed f16-pair h1 (for wave2)
    __shared__ __align__(16) f4    sh_z2a[2][64];    // raw Wih2.h1

    const int tid  = threadIdx.x;
    const int wave = tid >> 6;
    const int lane = tid & 63;
    const int row  = (lane < H) ? lane : (H - 1);

    for (int i = tid; i < TSTEPS / 4; i += 256)
        ((f4*)sh_x)[i] = ((const f4*)x)[i];

    // ---- per-wave matrix as 104 packed f16-pair registers ----
    const float* Mp = (wave == 0) ? Whh1 : (wave == 1) ? Whh2 : Wih2;
    DECLG(0) DECLG(1) DECLG(2) DECLG(3)
    LOADG(0, Mp + (0 * H + row) * H)
    LOADG(1, Mp + (1 * H + row) * H)
    LOADG(2, Mp + (2 * H + row) * H)
    LOADG(3, Mp + (3 * H + row) * H)

    f4 b1v, wx4, b2v;
#pragma unroll
    for (int g = 0; g < 4; ++g) {
        b1v[g] = bih1[g * H + row] + bhh1[g * H + row];
        wx4[g] = Wih1[g * H + row];
        b2v[g] = bih2[g * H + row] + bhh2[g * H + row];
    }
    const float wlin = (lane < H) ? Wlin[lane] : 0.0f;
    const float bl   = blin[0];

    if (tid < 64) {
        sh_h1f[tid] = 0.0f;
        sh_h2f[0][tid] = 0.0f; sh_h2f[1][tid] = 0.0f;
        sh_hpk1[0][tid] = 0;   sh_hpk1[1][tid] = 0;
        sh_z2a[0][tid] = (f4)0.0f; sh_z2a[1][tid] = (f4)0.0f;
    }
    float c1 = 0.0f, c2 = 0.0f;
    int hpk1reg = 0, hpk2reg = 0;   // packed f16 pairs of h1(e-1) / h2(s-1)
    __syncthreads();

#pragma unroll 1
    for (int e = 0; e < TSTEPS + 3; ++e) {
        PING(0) PING(1) PING(2) PING(3)

        if (wave == 0) {
            if (e < TSTEPS) {
                const float xv = sh_x[e];                  // early issue, late use
                float a0 = b1v[0], a1 = b1v[1], a2 = b1v[2], a3 = b1v[3];
                const int _hs = hpk1reg;
                DOT26
                a0 = fmaf(wx4[0], xv, a0); a1 = fmaf(wx4[1], xv, a1);
                a2 = fmaf(wx4[2], xv, a2); a3 = fmaf(wx4[3], xv, a3);
                const float ig = sigmoidf_fast(a0), fg = sigmoidf_fast(a1);
                const float gg = tanhf_fast(a2),    og = sigmoidf_fast(a3);
                c1 = fmaf(fg, c1, ig * gg);
                const float h1n = (lane < H) ? og * tanhf_fast(c1) : 0.0f;
                sh_h1f[lane] = h1n;
                const f2 hp = ((const f2*)sh_h1f)[lane & 31];   // lane j: {h[2j],h[2j+1]}
                h2 pk; pk[0] = (_Float16)hp[0]; pk[1] = (_Float16)hp[1];
                hpk1reg = ash(pk);
                sh_hpk1[e & 1][lane] = hpk1reg;                 // for wave2
            }
        } else if (wave == 2) {
            if (e >= 1 && e < TSTEPS + 1) {
                const int s = e - 1;
                const int _hs = sh_hpk1[s & 1][lane];           // written epoch s
                float a0 = 0.0f, a1 = 0.0f, a2 = 0.0f, a3 = 0.0f;
                DOT26
                f4 z; z[0] = a0; z[1] = a1; z[2] = a2; z[3] = a3;
                ((f4*)sh_z2a[s & 1])[lane] = z;
            }
        } else if (wave == 1) {
            if (e >= 2 && e < TSTEPS + 2) {
                const int s = e - 2;
                const f4 za = ((const f4*)sh_z2a[s & 1])[lane]; // issue早 — used after dot
                // u2(s) = b2 + Whh2.h2(s-1): depends only on last epoch's pack
                float a0 = b2v[0], a1 = b2v[1], a2 = b2v[2], a3 = b2v[3];
                const int _hs = hpk2reg;
                DOT26
                const float ig = sigmoidf_fast(za[0] + a0);
                const float fg = sigmoidf_fast(za[1] + a1);
                const float gg = tanhf_fast   (za[2] + a2);
                const float og = sigmoidf_fast(za[3] + a3);
                c2 = fmaf(fg, c2, ig * gg);
                const float h2n = (lane < H) ? og * tanhf_fast(c2) : 0.0f;
                sh_h2f[s & 1][lane] = h2n;                      // for wave3 + pack hop
                const f2 hp = ((const f2*)sh_h2f[s & 1])[lane & 31];
                h2 pk; pk[0] = (_Float16)hp[0]; pk[1] = (_Float16)hp[1];
                hpk2reg = ash(pk);
            }
        } else {
            if (e >= 3) {
                const int s = e - 3;
                const float hv = sh_h2f[s & 1][lane];           // written epoch s+2
                float p = hv * wlin;
                p += __shfl_down(p, 32);
                p += __shfl_down(p, 16);
                p += __shfl_down(p, 8);
                p += __shfl_down(p, 4);
                p += __shfl_down(p, 2);
                p += __shfl_down(p, 1);
                if (lane == 0) sh_out[s] = p + bl;
            }
        }
        __syncthreads();
    }

    for (int i = tid; i < TSTEPS / 4; i += 256)
        ((f4*)out)[i] = ((const f4*)sh_out)[i];
}

extern "C" void kernel_launch(void* const* d_in, const int* in_sizes, int n_in,
                              void* d_out, int out_size, void* d_ws, size_t ws_size,
                              hipStream_t stream) {
    const float* x    = (const float*)d_in[0];
    const float* Wih1 = (const float*)d_in[1];
    const float* Whh1 = (const float*)d_in[2];
    const float* bih1 = (const float*)d_in[3];
    const float* bhh1 = (const float*)d_in[4];
    const float* Wih2 = (const float*)d_in[5];
    const float* Whh2 = (const float*)d_in[6];
    const float* bih2 = (const float*)d_in[7];
    const float* bhh2 = (const float*)d_in[8];
    const float* Wlin = (const float*)d_in[9];
    const float* blin = (const float*)d_in[10];
    float* out = (float*)d_out;

    lstm2_dot2_kernel<<<1, 256, 0, stream>>>(
        x, Wih1, Whh1, bih1, bhh1, Wih2, Whh2, bih2, bhh2, Wlin, blin, out);
}

// Round 11
// 4013.126 us; speedup vs baseline: 1.4527x; 1.0297x over previous
//
#include <hip/hip_runtime.h>

#define TSTEPS 8192
#define H 51

typedef float  f2 __attribute__((ext_vector_type(2)));
typedef float  f4 __attribute__((ext_vector_type(4)));
typedef int    i4 __attribute__((ext_vector_type(4)));
typedef int    i2 __attribute__((ext_vector_type(2)));
typedef _Float16 h2 __attribute__((ext_vector_type(2)));

__device__ __forceinline__ int rl_i(int v, int k) { return __builtin_amdgcn_readlane(v, k); }
__device__ __forceinline__ h2 asp(int v) { union { int i; h2 h; } u; u.i = v; return u.h; }
__device__ __forceinline__ int ash(h2 v) { union { int i; h2 h; } u; u.h = v; return u.i; }

__device__ __forceinline__ float fdot2(h2 a, h2 b, float c) {
#if __has_builtin(__builtin_amdgcn_fdot2)
    return __builtin_amdgcn_fdot2(a, b, c, false);
#else
    return fmaf((float)a[0], (float)b[0], fmaf((float)a[1], (float)b[1], c));
#endif
}
__device__ __forceinline__ float sigmoidf_fast(float x) {
    return __builtin_amdgcn_rcpf(1.0f + __expf(-x));
}
__device__ __forceinline__ float tanhf_fast(float x) {
    x = fminf(fmaxf(x, -15.0f), 15.0f);
    float t = __expf(-2.0f * x);
    return (1.0f - t) * __builtin_amdgcn_rcpf(1.0f + t);
}
// f16-RNE pack of one k-pair of a weight row
__device__ __forceinline__ int packpair(const float* Wrow, int j) {
    const float w0 = (2 * j < H) ? Wrow[2 * j] : 0.0f;
    const float w1 = (2 * j + 1 < H) ? Wrow[2 * j + 1] : 0.0f;
    h2 p; p[0] = (_Float16)w0; p[1] = (_Float16)w1; return ash(p);
}
// In-register pair gather: lane j <- {h(lane 2j), h(lane 2j+1)} as f16x2 (RNE)
__device__ __forceinline__ int packpairs_bperm(float hval, int a0, int a1) {
    const int hi = __float_as_int(hval);
    const float v0 = __int_as_float(__builtin_amdgcn_ds_bpermute(a0, hi));
    const float v1 = __int_as_float(__builtin_amdgcn_ds_bpermute(a1, hi));
    h2 pk; pk[0] = (_Float16)v0; pk[1] = (_Float16)v1;
    return ash(pk);
}

// R11 = R10 (f16-pair weights under the 132-VGPR wall + v_dot2) minus two
// unforced serializations R10's counters exposed (~1210 cyc/epoch, VALU
// instrs ~2x the math):
//  (a) PIN hoisted OUT of the loop — an asm result can never be remat'd, so
//      one pin binds forever; per-epoch pins were forcing 28 reg
//      materializations/wave/epoch.
//  (b) h-pair packing via ds_bpermute (in-register lane gather) instead of
//      LDS write->wait->read round-trip (~120-150 cyc) on both critical waves.
// Pipeline (4 waves, 1/SIMD, 1 barrier/epoch):
//   wave0 @e: h1(e)   = cell1(Whh1.h1(e-1) + x[e])    [in-wave, dot2]
//   wave2 @e: z2a(e-1)= Wih2.h1(e-1)                   [dot2, 1 LDS read]
//   wave1 @e: u2 dot first (hides z2a latency); h2(e-2)= cell2(u2+z2a)
//   wave3 @e: out(e-3)= Wlin.h2(e-3)+blin              [off critical path]
#define DECLG(g) i4 wq##g##_0, wq##g##_1, wq##g##_2, wq##g##_3, wq##g##_4, wq##g##_5; i2 wq##g##_6;
#define LOADG(g, RP) { const float* _r = (RP); \
    i4 t0 = {packpair(_r,0),  packpair(_r,1),  packpair(_r,2),  packpair(_r,3)};  wq##g##_0 = t0; \
    i4 t1 = {packpair(_r,4),  packpair(_r,5),  packpair(_r,6),  packpair(_r,7)};  wq##g##_1 = t1; \
    i4 t2 = {packpair(_r,8),  packpair(_r,9),  packpair(_r,10), packpair(_r,11)}; wq##g##_2 = t2; \
    i4 t3 = {packpair(_r,12), packpair(_r,13), packpair(_r,14), packpair(_r,15)}; wq##g##_3 = t3; \
    i4 t4 = {packpair(_r,16), packpair(_r,17), packpair(_r,18), packpair(_r,19)}; wq##g##_4 = t4; \
    i4 t5 = {packpair(_r,20), packpair(_r,21), packpair(_r,22), packpair(_r,23)}; wq##g##_5 = t5; \
    i2 t6 = {packpair(_r,24), packpair(_r,25)};                                   wq##g##_6 = t6; }
#define PING(g) asm("" : "+v"(wq##g##_0), "+v"(wq##g##_1), "+v"(wq##g##_2), \
                        "+v"(wq##g##_3), "+v"(wq##g##_4), "+v"(wq##g##_5), "+v"(wq##g##_6));
#define DJ(j,q,e) { const h2 _hb = asp(rl_i(_hs, j)); \
    a0 = fdot2(asp(wq0_##q[e]), _hb, a0); \
    a1 = fdot2(asp(wq1_##q[e]), _hb, a1); \
    a2 = fdot2(asp(wq2_##q[e]), _hb, a2); \
    a3 = fdot2(asp(wq3_##q[e]), _hb, a3); }
#define DOT26 \
    DJ(0,0,0) DJ(1,0,1) DJ(2,0,2) DJ(3,0,3) DJ(4,1,0) DJ(5,1,1) DJ(6,1,2) DJ(7,1,3) \
    DJ(8,2,0) DJ(9,2,1) DJ(10,2,2) DJ(11,2,3) DJ(12,3,0) DJ(13,3,1) DJ(14,3,2) DJ(15,3,3) \
    DJ(16,4,0) DJ(17,4,1) DJ(18,4,2) DJ(19,4,3) DJ(20,5,0) DJ(21,5,1) DJ(22,5,2) DJ(23,5,3) \
    DJ(24,6,0) DJ(25,6,1)

__global__ __launch_bounds__(256) __attribute__((amdgpu_waves_per_eu(1, 1)))
void lstm2_bperm_kernel(const float* __restrict__ x,
                        const float* __restrict__ Wih1,
                        const float* __restrict__ Whh1,
                        const float* __restrict__ bih1,
                        const float* __restrict__ bhh1,
                        const float* __restrict__ Wih2,
                        const float* __restrict__ Whh2,
                        const float* __restrict__ bih2,
                        const float* __restrict__ bhh2,
                        const float* __restrict__ Wlin,
                        const float* __restrict__ blin,
                        float* __restrict__ out)
{
    __shared__ __align__(16) float sh_x[TSTEPS];
    __shared__ __align__(16) float sh_out[TSTEPS];
    __shared__ __align__(16) float sh_h2f[2][64];    // f32 h2 (for wave3's out dot)
    __shared__ __align__(16) int   sh_hpk1[2][64];   // packed f16-pair h1 (for wave2)
    __shared__ __align__(16) f4    sh_z2a[2][64];    // raw Wih2.h1

    const int tid  = threadIdx.x;
    const int wave = tid >> 6;
    const int lane = tid & 63;
    const int row  = (lane < H) ? lane : (H - 1);
    const int pa0  = (2 * lane) * 4;       // bpermute byte addrs (lane 2j, 2j+1)
    const int pa1  = (2 * lane + 1) * 4;

    for (int i = tid; i < TSTEPS / 4; i += 256)
        ((f4*)sh_x)[i] = ((const f4*)x)[i];

    // ---- per-wave matrix as 104 packed f16-pair registers ----
    const float* Mp = (wave == 0) ? Whh1 : (wave == 1) ? Whh2 : Wih2;
    DECLG(0) DECLG(1) DECLG(2) DECLG(3)
    LOADG(0, Mp + (0 * H + row) * H)
    LOADG(1, Mp + (1 * H + row) * H)
    LOADG(2, Mp + (2 * H + row) * H)
    LOADG(3, Mp + (3 * H + row) * H)
    // Pin ONCE: asm results are never rematerializable; no per-epoch copies.
    PING(0) PING(1) PING(2) PING(3)

    f4 b1v, wx4, b2v;
#pragma unroll
    for (int g = 0; g < 4; ++g) {
        b1v[g] = bih1[g * H + row] + bhh1[g * H + row];
        wx4[g] = Wih1[g * H + row];
        b2v[g] = bih2[g * H + row] + bhh2[g * H + row];
    }
    const float wlin = (lane < H) ? Wlin[lane] : 0.0f;
    const float bl   = blin[0];

    if (tid < 64) {
        sh_h2f[0][tid] = 0.0f; sh_h2f[1][tid] = 0.0f;
        sh_hpk1[0][tid] = 0;   sh_hpk1[1][tid] = 0;
        sh_z2a[0][tid] = (f4)0.0f; sh_z2a[1][tid] = (f4)0.0f;
    }
    float c1 = 0.0f, c2 = 0.0f;
    int hpk1reg = 0, hpk2reg = 0;   // packed f16 pairs of h1(e-1) / h2(s-1)
    __syncthreads();

#pragma unroll 1
    for (int e = 0; e < TSTEPS + 3; ++e) {
        if (wave == 0) {
            if (e < TSTEPS) {
                const float xv = sh_x[e];                  // issued early, used late
                float a0 = b1v[0], a1 = b1v[1], a2 = b1v[2], a3 = b1v[3];
                const int _hs = hpk1reg;
                DOT26
                a0 = fmaf(wx4[0], xv, a0); a1 = fmaf(wx4[1], xv, a1);
                a2 = fmaf(wx4[2], xv, a2); a3 = fmaf(wx4[3], xv, a3);
                const float ig = sigmoidf_fast(a0), fg = sigmoidf_fast(a1);
                const float gg = tanhf_fast(a2),    og = sigmoidf_fast(a3);
                c1 = fmaf(fg, c1, ig * gg);
                const float h1n = (lane < H) ? og * tanhf_fast(c1) : 0.0f;
                hpk1reg = packpairs_bperm(h1n, pa0, pa1);       // in-register pack
                sh_hpk1[e & 1][lane] = hpk1reg;                 // for wave2
            }
        } else if (wave == 2) {
            if (e >= 1 && e < TSTEPS + 1) {
                const int s = e - 1;
                const int _hs = sh_hpk1[s & 1][lane];           // written epoch s
                float a0 = 0.0f, a1 = 0.0f, a2 = 0.0f, a3 = 0.0f;
                DOT26
                f4 z; z[0] = a0; z[1] = a1; z[2] = a2; z[3] = a3;
                ((f4*)sh_z2a[s & 1])[lane] = z;
            }
        } else if (wave == 1) {
            if (e >= 2 && e < TSTEPS + 2) {
                const int s = e - 2;
                const f4 za = ((const f4*)sh_z2a[s & 1])[lane]; // issued early
                // u2(s) = b2 + Whh2.h2(s-1): only needs last epoch's pack
                float a0 = b2v[0], a1 = b2v[1], a2 = b2v[2], a3 = b2v[3];
                const int _hs = hpk2reg;
                DOT26
                const float ig = sigmoidf_fast(za[0] + a0);
                const float fg = sigmoidf_fast(za[1] + a1);
                const float gg = tanhf_fast   (za[2] + a2);
                const float og = sigmoidf_fast(za[3] + a3);
                c2 = fmaf(fg, c2, ig * gg);
                const float h2n = (lane < H) ? og * tanhf_fast(c2) : 0.0f;
                sh_h2f[s & 1][lane] = h2n;                      // for wave3 (off-path)
                hpk2reg = packpairs_bperm(h2n, pa0, pa1);       // in-register pack
            }
        } else {
            if (e >= 3) {
                const int s = e - 3;
                const float hv = sh_h2f[s & 1][lane];           // written epoch s+2
                float p = hv * wlin;
                p += __shfl_down(p, 32);
                p += __shfl_down(p, 16);
                p += __shfl_down(p, 8);
                p += __shfl_down(p, 4);
                p += __shfl_down(p, 2);
                p += __shfl_down(p, 1);
                if (lane == 0) sh_out[s] = p + bl;
            }
        }
        __syncthreads();
    }

    for (int i = tid; i < TSTEPS / 4; i += 256)
        ((f4*)out)[i] = ((const f4*)sh_out)[i];
}

extern "C" void kernel_launch(void* const* d_in, const int* in_sizes, int n_in,
                              void* d_out, int out_size, void* d_ws, size_t ws_size,
                              hipStream_t stream) {
    const float* x    = (const float*)d_in[0];
    const float* Wih1 = (const float*)d_in[1];
    const float* Whh1 = (const float*)d_in[2];
    const float* bih1 = (const float*)d_in[3];
    const float* bhh1 = (const float*)d_in[4];
    const float* Wih2 = (const float*)d_in[5];
    const float* Whh2 = (const float*)d_in[6];
    const float* bih2 = (const float*)d_in[7];
    const float* bhh2 = (const float*)d_in[8];
    const float* Wlin = (const float*)d_in[9];
    const float* blin = (const float*)d_in[10];
    float* out = (float*)d_out;

    lstm2_bperm_kernel<<<1, 256, 0, stream>>>(
        x, Wih1, Whh1, bih1, bhh1, Wih2, Whh2, bih2, bhh2, Wlin, blin, out);
}

// Round 12
// 3264.089 us; speedup vs baseline: 1.7861x; 1.2295x over previous
//
#include <hip/hip_runtime.h>

#define TSTEPS 8192
#define H 51
#define SE 4                     // timesteps per barrier epoch
#define NEP (TSTEPS / SE + 3)    // 4 pipeline stages -> +3 epochs

typedef float  f2 __attribute__((ext_vector_type(2)));
typedef float  f4 __attribute__((ext_vector_type(4)));
typedef int    i4 __attribute__((ext_vector_type(4)));
typedef int    i2 __attribute__((ext_vector_type(2)));
typedef _Float16 h2 __attribute__((ext_vector_type(2)));

__device__ __forceinline__ int rl_i(int v, int k) { return __builtin_amdgcn_readlane(v, k); }
__device__ __forceinline__ h2 asp(int v) { union { int i; h2 h; } u; u.i = v; return u.h; }
__device__ __forceinline__ int ash(h2 v) { union { int i; h2 h; } u; u.h = v; return u.i; }

__device__ __forceinline__ float fdot2(h2 a, h2 b, float c) {
#if __has_builtin(__builtin_amdgcn_fdot2)
    return __builtin_amdgcn_fdot2(a, b, c, false);
#else
    return fmaf((float)a[0], (float)b[0], fmaf((float)a[1], (float)b[1], c));
#endif
}
__device__ __forceinline__ float sigmoidf_fast(float x) {
    return __builtin_amdgcn_rcpf(1.0f + __expf(-x));
}
__device__ __forceinline__ float tanhf_fast(float x) {
    x = fminf(fmaxf(x, -15.0f), 15.0f);
    float t = __expf(-2.0f * x);
    return (1.0f - t) * __builtin_amdgcn_rcpf(1.0f + t);
}
__device__ __forceinline__ int packpair(const float* Wrow, int j) {
    const float w0 = (2 * j < H) ? Wrow[2 * j] : 0.0f;
    const float w1 = (2 * j + 1 < H) ? Wrow[2 * j + 1] : 0.0f;
    h2 p; p[0] = (_Float16)w0; p[1] = (_Float16)w1; return ash(p);
}
// lane j <- {h(lane 2j), h(lane 2j+1)} packed to f16x2 (RNE), in-register
__device__ __forceinline__ int packpairs_bperm(float hval, int a0, int a1) {
    const int hi = __float_as_int(hval);
    const float v0 = __int_as_float(__builtin_amdgcn_ds_bpermute(a0, hi));
    const float v1 = __int_as_float(__builtin_amdgcn_ds_bpermute(a1, hi));
    h2 pk; pk[0] = (_Float16)v0; pk[1] = (_Float16)v1;
    return ash(pk);
}

// R12 = R11 + SE=4 timesteps per barrier epoch. R11's counters: each wave
// issues only ~270 cyc of VALU per 1175-cyc epoch -> ~650 cyc/epoch is
// barrier arrive/release + lgkm drain + post-barrier LDS latency, paid per
// TIMESTEP. The in-wave recurrences (h1 in wave0, h2/u2 in wave1) are pure
// register self-loops, so each wave runs 4 consecutive steps per epoch;
// cross-wave handoffs stay pipelined at 1-epoch delay carrying 4 steps each.
// Barriers: 8192 -> 2051. Weights: f16 pairs (104 VGPR/wave, under the
// 132-VGPR wall), v_dot2_f32_f16, pinned once (asm results never remat).
//   wave0 @e: steps 4e..4e+3   : h1 = cell1(Whh1.h1 + x)   [in-wave serial]
//   wave2 @e: steps 4(e-1)+j   : z2a = Wih2.h1             [4 indep dots]
//   wave1 @e: steps 4(e-2)+j   : u2 dot (in-wave) + cell2  [in-wave serial]
//   wave3 @e: steps 4(e-3)+j   : out = Wlin.h2 + blin      [off-path]
#define DECLG(g) i4 wq##g##_0, wq##g##_1, wq##g##_2, wq##g##_3, wq##g##_4, wq##g##_5; i2 wq##g##_6;
#define LOADG(g, RP) { const float* _r = (RP); \
    i4 t0 = {packpair(_r,0),  packpair(_r,1),  packpair(_r,2),  packpair(_r,3)};  wq##g##_0 = t0; \
    i4 t1 = {packpair(_r,4),  packpair(_r,5),  packpair(_r,6),  packpair(_r,7)};  wq##g##_1 = t1; \
    i4 t2 = {packpair(_r,8),  packpair(_r,9),  packpair(_r,10), packpair(_r,11)}; wq##g##_2 = t2; \
    i4 t3 = {packpair(_r,12), packpair(_r,13), packpair(_r,14), packpair(_r,15)}; wq##g##_3 = t3; \
    i4 t4 = {packpair(_r,16), packpair(_r,17), packpair(_r,18), packpair(_r,19)}; wq##g##_4 = t4; \
    i4 t5 = {packpair(_r,20), packpair(_r,21), packpair(_r,22), packpair(_r,23)}; wq##g##_5 = t5; \
    i2 t6 = {packpair(_r,24), packpair(_r,25)};                                   wq##g##_6 = t6; }
#define PING(g) asm("" : "+v"(wq##g##_0), "+v"(wq##g##_1), "+v"(wq##g##_2), \
                        "+v"(wq##g##_3), "+v"(wq##g##_4), "+v"(wq##g##_5), "+v"(wq##g##_6));
#define DJ(j,q,e) { const h2 _hb = asp(rl_i(_hs, j)); \
    a0 = fdot2(asp(wq0_##q[e]), _hb, a0); \
    a1 = fdot2(asp(wq1_##q[e]), _hb, a1); \
    a2 = fdot2(asp(wq2_##q[e]), _hb, a2); \
    a3 = fdot2(asp(wq3_##q[e]), _hb, a3); }
#define DOT26 \
    DJ(0,0,0) DJ(1,0,1) DJ(2,0,2) DJ(3,0,3) DJ(4,1,0) DJ(5,1,1) DJ(6,1,2) DJ(7,1,3) \
    DJ(8,2,0) DJ(9,2,1) DJ(10,2,2) DJ(11,2,3) DJ(12,3,0) DJ(13,3,1) DJ(14,3,2) DJ(15,3,3) \
    DJ(16,4,0) DJ(17,4,1) DJ(18,4,2) DJ(19,4,3) DJ(20,5,0) DJ(21,5,1) DJ(22,5,2) DJ(23,5,3) \
    DJ(24,6,0) DJ(25,6,1)

__global__ __launch_bounds__(256) __attribute__((amdgpu_waves_per_eu(1, 1)))
void lstm2_b4_kernel(const float* __restrict__ x,
                     const float* __restrict__ Wih1,
                     const float* __restrict__ Whh1,
                     const float* __restrict__ bih1,
                     const float* __restrict__ bhh1,
                     const float* __restrict__ Wih2,
                     const float* __restrict__ Whh2,
                     const float* __restrict__ bih2,
                     const float* __restrict__ bhh2,
                     const float* __restrict__ Wlin,
                     const float* __restrict__ blin,
                     float* __restrict__ out)
{
    __shared__ __align__(16) float sh_x[TSTEPS];
    __shared__ __align__(16) float sh_out[TSTEPS];
    __shared__ __align__(16) int   sh_hpk1[2][SE][64];  // packed h1 (wave0 -> wave2)
    __shared__ __align__(16) f4    sh_z2a[2][SE][64];   // raw Wih2.h1 (wave2 -> wave1)
    __shared__ __align__(16) float sh_h2f[2][SE][64];   // f32 h2 (wave1 -> wave3)

    const int tid  = threadIdx.x;
    const int wave = tid >> 6;
    const int lane = tid & 63;
    const int row  = (lane < H) ? lane : (H - 1);
    const int pa0  = (2 * lane) * 4;
    const int pa1  = (2 * lane + 1) * 4;

    for (int i = tid; i < TSTEPS / 4; i += 256)
        ((f4*)sh_x)[i] = ((const f4*)x)[i];

    // ---- per-wave matrix as 104 packed f16-pair registers, pinned once ----
    const float* Mp = (wave == 0) ? Whh1 : (wave == 1) ? Whh2 : Wih2;
    DECLG(0) DECLG(1) DECLG(2) DECLG(3)
    LOADG(0, Mp + (0 * H + row) * H)
    LOADG(1, Mp + (1 * H + row) * H)
    LOADG(2, Mp + (2 * H + row) * H)
    LOADG(3, Mp + (3 * H + row) * H)
    PING(0) PING(1) PING(2) PING(3)

    f4 b1v, wx4, b2v;
#pragma unroll
    for (int g = 0; g < 4; ++g) {
        b1v[g] = bih1[g * H + row] + bhh1[g * H + row];
        wx4[g] = Wih1[g * H + row];
        b2v[g] = bih2[g * H + row] + bhh2[g * H + row];
    }
    const float wlin = (lane < H) ? Wlin[lane] : 0.0f;
    const float bl   = blin[0];

    if (tid < 64) {
#pragma unroll
        for (int b = 0; b < 2; ++b)
#pragma unroll
            for (int j = 0; j < SE; ++j) {
                sh_hpk1[b][j][tid] = 0;
                sh_z2a[b][j][tid] = (f4)0.0f;
                sh_h2f[b][j][tid] = 0.0f;
            }
    }
    float c1 = 0.0f, c2 = 0.0f;
    int hpk1reg = 0, hpk2reg = 0;
    __syncthreads();

#pragma unroll 1
    for (int e = 0; e < NEP; ++e) {
        if (wave == 0) {
            // ---- steps 4e..4e+3: layer-1 self-loop, fully in-wave ----
            if (e < TSTEPS / SE) {
                const f4 xs = ((const f4*)sh_x)[e];   // 4 x values, one b128
#pragma unroll
                for (int j = 0; j < SE; ++j) {
                    float a0 = b1v[0], a1 = b1v[1], a2 = b1v[2], a3 = b1v[3];
                    const int _hs = hpk1reg;
                    DOT26
                    const float xv = xs[j];
                    a0 = fmaf(wx4[0], xv, a0); a1 = fmaf(wx4[1], xv, a1);
                    a2 = fmaf(wx4[2], xv, a2); a3 = fmaf(wx4[3], xv, a3);
                    const float ig = sigmoidf_fast(a0), fg = sigmoidf_fast(a1);
                    const float gg = tanhf_fast(a2),    og = sigmoidf_fast(a3);
                    c1 = fmaf(fg, c1, ig * gg);
                    const float h1n = (lane < H) ? og * tanhf_fast(c1) : 0.0f;
                    hpk1reg = packpairs_bperm(h1n, pa0, pa1);
                    sh_hpk1[e & 1][j][lane] = hpk1reg;
                }
            }
        } else if (wave == 2) {
            // ---- steps 4(e-1)+j: z2a = Wih2.h1 (4 independent dots) ----
            if (e >= 1 && e <= TSTEPS / SE) {
                int hp[SE];
#pragma unroll
                for (int j = 0; j < SE; ++j) hp[j] = sh_hpk1[(e - 1) & 1][j][lane];
#pragma unroll
                for (int j = 0; j < SE; ++j) {
                    const int _hs = hp[j];
                    float a0 = 0.0f, a1 = 0.0f, a2 = 0.0f, a3 = 0.0f;
                    DOT26
                    f4 z; z[0] = a0; z[1] = a1; z[2] = a2; z[3] = a3;
                    sh_z2a[e & 1][j][lane] = z;
                }
            }
        } else if (wave == 1) {
            // ---- steps 4(e-2)+j: u2 dot (in-wave h2 self-loop) + cell2 ----
            if (e >= 2 && e <= TSTEPS / SE + 1) {
                f4 za[SE];
#pragma unroll
                for (int j = 0; j < SE; ++j) za[j] = sh_z2a[(e - 1) & 1][j][lane];
#pragma unroll
                for (int j = 0; j < SE; ++j) {
                    float a0 = b2v[0], a1 = b2v[1], a2 = b2v[2], a3 = b2v[3];
                    const int _hs = hpk2reg;
                    DOT26
                    const float ig = sigmoidf_fast(za[j][0] + a0);
                    const float fg = sigmoidf_fast(za[j][1] + a1);
                    const float gg = tanhf_fast   (za[j][2] + a2);
                    const float og = sigmoidf_fast(za[j][3] + a3);
                    c2 = fmaf(fg, c2, ig * gg);
                    const float h2n = (lane < H) ? og * tanhf_fast(c2) : 0.0f;
                    sh_h2f[e & 1][j][lane] = h2n;
                    hpk2reg = packpairs_bperm(h2n, pa0, pa1);
                }
            }
        } else {
            // ---- steps 4(e-3)+j: out = Wlin.h2 + blin (off critical path) ----
            if (e >= 3) {
                const int base = (e - 3) * SE;
                float p0 = sh_h2f[(e - 1) & 1][0][lane] * wlin;
                float p1 = sh_h2f[(e - 1) & 1][1][lane] * wlin;
                float p2 = sh_h2f[(e - 1) & 1][2][lane] * wlin;
                float p3 = sh_h2f[(e - 1) & 1][3][lane] * wlin;
#pragma unroll
                for (int off = 32; off >= 1; off >>= 1) {   // interleaved butterflies
                    p0 += __shfl_down(p0, off);
                    p1 += __shfl_down(p1, off);
                    p2 += __shfl_down(p2, off);
                    p3 += __shfl_down(p3, off);
                }
                if (lane == 0) {
                    sh_out[base + 0] = p0 + bl;
                    sh_out[base + 1] = p1 + bl;
                    sh_out[base + 2] = p2 + bl;
                    sh_out[base + 3] = p3 + bl;
                }
            }
        }
        __syncthreads();
    }

    for (int i = tid; i < TSTEPS / 4; i += 256)
        ((f4*)out)[i] = ((const f4*)sh_out)[i];
}

extern "C" void kernel_launch(void* const* d_in, const int* in_sizes, int n_in,
                              void* d_out, int out_size, void* d_ws, size_t ws_size,
                              hipStream_t stream) {
    const float* x    = (const float*)d_in[0];
    const float* Wih1 = (const float*)d_in[1];
    const float* Whh1 = (const float*)d_in[2];
    const float* bih1 = (const float*)d_in[3];
    const float* bhh1 = (const float*)d_in[4];
    const float* Wih2 = (const float*)d_in[5];
    const float* Whh2 = (const float*)d_in[6];
    const float* bih2 = (const float*)d_in[7];
    const float* bhh2 = (const float*)d_in[8];
    const float* Wlin = (const float*)d_in[9];
    const float* blin = (const float*)d_in[10];
    float* out = (float*)d_out;

    lstm2_b4_kernel<<<1, 256, 0, stream>>>(
        x, Wih1, Whh1, bih1, bhh1, Wih2, Whh2, bih2, bhh2, Wlin, blin, out);
}

// Round 13
// 3231.286 us; speedup vs baseline: 1.8042x; 1.0102x over previous
//
#include <hip/hip_runtime.h>

#define TSTEPS 8192
#define H 51
#define SE 8                     // timesteps per barrier epoch
#define NEPOCH (TSTEPS / SE + 3) // 4 pipeline stages -> +3 epochs

typedef float  f2 __attribute__((ext_vector_type(2)));
typedef float  f4 __attribute__((ext_vector_type(4)));
typedef int    i4 __attribute__((ext_vector_type(4)));
typedef int    i2 __attribute__((ext_vector_type(2)));
typedef _Float16 h2 __attribute__((ext_vector_type(2)));

__device__ __forceinline__ int rl_i(int v, int k) { return __builtin_amdgcn_readlane(v, k); }
__device__ __forceinline__ h2 asp(int v) { union { int i; h2 h; } u; u.i = v; return u.h; }
__device__ __forceinline__ int ash(h2 v) { union { int i; h2 h; } u; u.h = v; return u.i; }

__device__ __forceinline__ float fdot2(h2 a, h2 b, float c) {
#if __has_builtin(__builtin_amdgcn_fdot2)
    return __builtin_amdgcn_fdot2(a, b, c, false);
#else
    return fmaf((float)a[0], (float)b[0], fmaf((float)a[1], (float)b[1], c));
#endif
}
__device__ __forceinline__ float sigmoidf_fast(float x) {
    return __builtin_amdgcn_rcpf(1.0f + __expf(-x));
}
__device__ __forceinline__ float tanhf_fast(float x) {
    x = fminf(fmaxf(x, -15.0f), 15.0f);
    float t = __expf(-2.0f * x);
    return (1.0f - t) * __builtin_amdgcn_rcpf(1.0f + t);
}
__device__ __forceinline__ int packpair(const float* Wrow, int j) {
    const float w0 = (2 * j < H) ? Wrow[2 * j] : 0.0f;
    const float w1 = (2 * j + 1 < H) ? Wrow[2 * j + 1] : 0.0f;
    h2 p; p[0] = (_Float16)w0; p[1] = (_Float16)w1; return ash(p);
}
// lane j <- {h(lane 2j), h(lane 2j+1)} packed to f16x2 (RNE), in-register
__device__ __forceinline__ int packpairs_bperm(float hval, int a0, int a1) {
    const int hi = __float_as_int(hval);
    const float v0 = __int_as_float(__builtin_amdgcn_ds_bpermute(a0, hi));
    const float v1 = __int_as_float(__builtin_amdgcn_ds_bpermute(a1, hi));
    h2 pk; pk[0] = (_Float16)v0; pk[1] = (_Float16)v1;
    return ash(pk);
}

// R13 = R12 + (a) SE=8 (barriers 2051->1027; per-step sync ~125->~60 cyc),
// (b) 8 accumulators per dot (chain depth 26->13: ~100 cyc/step less
// dependency stall on the serial waves), (c) x-FMA folded into acc init.
// Carried: f16-pair weights (104 VGPR/wave, under the 132-VGPR wall),
// v_dot2_f32_f16 w/ fp32 accum, PIN-once, bpermute h-pack, 4-wave pipeline:
//   wave0 @e: steps 8e..8e+7   : h1 = cell1(Whh1.h1 + x)   [in-wave serial]
//   wave2 @e: steps 8(e-1)+j   : z2a = Wih2.h1             [8 indep dots]
//   wave1 @e: steps 8(e-2)+j   : u2 dot (in-wave) + cell2  [in-wave serial]
//   wave3 @e: steps 8(e-3)+j   : out = Wlin.h2 + blin      [off-path]
#define DECLG(g) i4 wq##g##_0, wq##g##_1, wq##g##_2, wq##g##_3, wq##g##_4, wq##g##_5; i2 wq##g##_6;
#define LOADG(g, RP) { const float* _r = (RP); \
    i4 t0 = {packpair(_r,0),  packpair(_r,1),  packpair(_r,2),  packpair(_r,3)};  wq##g##_0 = t0; \
    i4 t1 = {packpair(_r,4),  packpair(_r,5),  packpair(_r,6),  packpair(_r,7)};  wq##g##_1 = t1; \
    i4 t2 = {packpair(_r,8),  packpair(_r,9),  packpair(_r,10), packpair(_r,11)}; wq##g##_2 = t2; \
    i4 t3 = {packpair(_r,12), packpair(_r,13), packpair(_r,14), packpair(_r,15)}; wq##g##_3 = t3; \
    i4 t4 = {packpair(_r,16), packpair(_r,17), packpair(_r,18), packpair(_r,19)}; wq##g##_4 = t4; \
    i4 t5 = {packpair(_r,20), packpair(_r,21), packpair(_r,22), packpair(_r,23)}; wq##g##_5 = t5; \
    i2 t6 = {packpair(_r,24), packpair(_r,25)};                                   wq##g##_6 = t6; }
#define PING(g) asm("" : "+v"(wq##g##_0), "+v"(wq##g##_1), "+v"(wq##g##_2), \
                        "+v"(wq##g##_3), "+v"(wq##g##_4), "+v"(wq##g##_5), "+v"(wq##g##_6));
// two interleaved accumulator sets: a* (even j) and b* (odd j) -> depth 13
#define DJA(j,q,e) { const h2 _hb = asp(rl_i(_hs, j)); \
    a0 = fdot2(asp(wq0_##q[e]), _hb, a0); \
    a1 = fdot2(asp(wq1_##q[e]), _hb, a1); \
    a2 = fdot2(asp(wq2_##q[e]), _hb, a2); \
    a3 = fdot2(asp(wq3_##q[e]), _hb, a3); }
#define DJB(j,q,e) { const h2 _hb = asp(rl_i(_hs, j)); \
    b0 = fdot2(asp(wq0_##q[e]), _hb, b0); \
    b1 = fdot2(asp(wq1_##q[e]), _hb, b1); \
    b2 = fdot2(asp(wq2_##q[e]), _hb, b2); \
    b3 = fdot2(asp(wq3_##q[e]), _hb, b3); }
#define DOT26 \
    DJA(0,0,0) DJB(1,0,1) DJA(2,0,2) DJB(3,0,3) DJA(4,1,0) DJB(5,1,1) DJA(6,1,2) DJB(7,1,3) \
    DJA(8,2,0) DJB(9,2,1) DJA(10,2,2) DJB(11,2,3) DJA(12,3,0) DJB(13,3,1) DJA(14,3,2) DJB(15,3,3) \
    DJA(16,4,0) DJB(17,4,1) DJA(18,4,2) DJB(19,4,3) DJA(20,5,0) DJB(21,5,1) DJA(22,5,2) DJB(23,5,3) \
    DJA(24,6,0) DJB(25,6,1)

__global__ __launch_bounds__(256) __attribute__((amdgpu_waves_per_eu(1, 1)))
void lstm2_b8_kernel(const float* __restrict__ x,
                     const float* __restrict__ Wih1,
                     const float* __restrict__ Whh1,
                     const float* __restrict__ bih1,
                     const float* __restrict__ bhh1,
                     const float* __restrict__ Wih2,
                     const float* __restrict__ Whh2,
                     const float* __restrict__ bih2,
                     const float* __restrict__ bhh2,
                     const float* __restrict__ Wlin,
                     const float* __restrict__ blin,
                     float* __restrict__ out)
{
    __shared__ __align__(16) float sh_x[TSTEPS];
    __shared__ __align__(16) float sh_out[TSTEPS];
    __shared__ __align__(16) int   sh_hpk1[2][SE][64];  // packed h1 (wave0 -> wave2)
    __shared__ __align__(16) f4    sh_z2a[2][SE][64];   // raw Wih2.h1 (wave2 -> wave1)
    __shared__ __align__(16) float sh_h2f[2][SE][64];   // f32 h2 (wave1 -> wave3)

    const int tid  = threadIdx.x;
    const int wave = tid >> 6;
    const int lane = tid & 63;
    const int row  = (lane < H) ? lane : (H - 1);
    const int pa0  = (2 * lane) * 4;
    const int pa1  = (2 * lane + 1) * 4;

    for (int i = tid; i < TSTEPS / 4; i += 256)
        ((f4*)sh_x)[i] = ((const f4*)x)[i];

    // ---- per-wave matrix as 104 packed f16-pair registers, pinned once ----
    const float* Mp = (wave == 0) ? Whh1 : (wave == 1) ? Whh2 : Wih2;
    DECLG(0) DECLG(1) DECLG(2) DECLG(3)
    LOADG(0, Mp + (0 * H + row) * H)
    LOADG(1, Mp + (1 * H + row) * H)
    LOADG(2, Mp + (2 * H + row) * H)
    LOADG(3, Mp + (3 * H + row) * H)
    PING(0) PING(1) PING(2) PING(3)

    f4 b1v, wx4, b2v;
#pragma unroll
    for (int g = 0; g < 4; ++g) {
        b1v[g] = bih1[g * H + row] + bhh1[g * H + row];
        wx4[g] = Wih1[g * H + row];
        b2v[g] = bih2[g * H + row] + bhh2[g * H + row];
    }
    const float wlin = (lane < H) ? Wlin[lane] : 0.0f;
    const float bl   = blin[0];

    if (tid < 64) {
#pragma unroll
        for (int b = 0; b < 2; ++b)
#pragma unroll
            for (int j = 0; j < SE; ++j) {
                sh_hpk1[b][j][tid] = 0;
                sh_z2a[b][j][tid] = (f4)0.0f;
                sh_h2f[b][j][tid] = 0.0f;
            }
    }
    float c1 = 0.0f, c2 = 0.0f;
    int hpk1reg = 0, hpk2reg = 0;
    __syncthreads();

#pragma unroll 1
    for (int e = 0; e < NEPOCH; ++e) {
        if (wave == 0) {
            // ---- steps 8e..8e+7: layer-1 self-loop, fully in-wave ----
            if (e < TSTEPS / SE) {
                const f4 xs0 = ((const f4*)sh_x)[2 * e];
                const f4 xs1 = ((const f4*)sh_x)[2 * e + 1];
#pragma unroll
                for (int j = 0; j < SE; ++j) {
                    const float xv = (j < 4) ? xs0[j & 3] : xs1[j & 3];
                    // x-FMA folded into acc init (off the post-dot tail)
                    float a0 = fmaf(wx4[0], xv, b1v[0]);
                    float a1 = fmaf(wx4[1], xv, b1v[1]);
                    float a2 = fmaf(wx4[2], xv, b1v[2]);
                    float a3 = fmaf(wx4[3], xv, b1v[3]);
                    float b0 = 0.0f, b1 = 0.0f, b2 = 0.0f, b3 = 0.0f;
                    const int _hs = hpk1reg;
                    DOT26
                    const float ig = sigmoidf_fast(a0 + b0), fg = sigmoidf_fast(a1 + b1);
                    const float gg = tanhf_fast(a2 + b2),    og = sigmoidf_fast(a3 + b3);
                    c1 = fmaf(fg, c1, ig * gg);
                    const float h1n = (lane < H) ? og * tanhf_fast(c1) : 0.0f;
                    hpk1reg = packpairs_bperm(h1n, pa0, pa1);
                    sh_hpk1[e & 1][j][lane] = hpk1reg;
                }
            }
        } else if (wave == 2) {
            // ---- steps 8(e-1)+j: z2a = Wih2.h1 (8 independent dots) ----
            if (e >= 1 && e <= TSTEPS / SE) {
                int hp[SE];
#pragma unroll
                for (int j = 0; j < SE; ++j) hp[j] = sh_hpk1[(e - 1) & 1][j][lane];
#pragma unroll
                for (int j = 0; j < SE; ++j) {
                    const int _hs = hp[j];
                    float a0 = 0.0f, a1 = 0.0f, a2 = 0.0f, a3 = 0.0f;
                    float b0 = 0.0f, b1 = 0.0f, b2 = 0.0f, b3 = 0.0f;
                    DOT26
                    f4 z; z[0] = a0 + b0; z[1] = a1 + b1; z[2] = a2 + b2; z[3] = a3 + b3;
                    sh_z2a[e & 1][j][lane] = z;
                }
            }
        } else if (wave == 1) {
            // ---- steps 8(e-2)+j: u2 dot (in-wave h2 self-loop) + cell2 ----
            if (e >= 2 && e <= TSTEPS / SE + 1) {
                f4 za[SE];
#pragma unroll
                for (int j = 0; j < SE; ++j) za[j] = sh_z2a[(e - 1) & 1][j][lane];
#pragma unroll
                for (int j = 0; j < SE; ++j) {
                    float a0 = b2v[0], a1 = b2v[1], a2 = b2v[2], a3 = b2v[3];
                    float b0 = 0.0f, b1 = 0.0f, b2 = 0.0f, b3 = 0.0f;
                    const int _hs = hpk2reg;
                    DOT26
                    const float ig = sigmoidf_fast(za[j][0] + a0 + b0);
                    const float fg = sigmoidf_fast(za[j][1] + a1 + b1);
                    const float gg = tanhf_fast   (za[j][2] + a2 + b2);
                    const float og = sigmoidf_fast(za[j][3] + a3 + b3);
                    c2 = fmaf(fg, c2, ig * gg);
                    const float h2n = (lane < H) ? og * tanhf_fast(c2) : 0.0f;
                    sh_h2f[e & 1][j][lane] = h2n;
                    hpk2reg = packpairs_bperm(h2n, pa0, pa1);
                }
            }
        } else {
            // ---- steps 8(e-3)+j: out = Wlin.h2 + blin (off critical path) ----
            if (e >= 3) {
                const int base = (e - 3) * SE;
                float p[SE];
#pragma unroll
                for (int j = 0; j < SE; ++j)
                    p[j] = sh_h2f[(e - 1) & 1][j][lane] * wlin;
#pragma unroll
                for (int off = 32; off >= 1; off >>= 1) {
#pragma unroll
                    for (int j = 0; j < SE; ++j) p[j] += __shfl_down(p[j], off);
                }
                if (lane == 0) {
#pragma unroll
                    for (int j = 0; j < SE; ++j) sh_out[base + j] = p[j] + bl;
                }
            }
        }
        __syncthreads();
    }

    for (int i = tid; i < TSTEPS / 4; i += 256)
        ((f4*)out)[i] = ((const f4*)sh_out)[i];
}

extern "C" void kernel_launch(void* const* d_in, const int* in_sizes, int n_in,
                              void* d_out, int out_size, void* d_ws, size_t ws_size,
                              hipStream_t stream) {
    const float* x    = (const float*)d_in[0];
    const float* Wih1 = (const float*)d_in[1];
    const float* Whh1 = (const float*)d_in[2];
    const float* bih1 = (const float*)d_in[3];
    const float* bhh1 = (const float*)d_in[4];
    const float* Wih2 = (const float*)d_in[5];
    const float* Whh2 = (const float*)d_in[6];
    const float* bih2 = (const float*)d_in[7];
    const float* bhh2 = (const float*)d_in[8];
    const float* Wlin = (const float*)d_in[9];
    const float* blin = (const float*)d_in[10];
    float* out = (float*)d_out;

    lstm2_b8_kernel<<<1, 256, 0, stream>>>(
        x, Wih1, Whh1, bih1, bhh1, Wih2, Whh2, bih2, bhh2, Wlin, blin, out);
}